// Round 23
// baseline (69.192 us; speedup 1.0000x reference)
//
#include <hip/hip_runtime.h>
#include <hip/hip_bf16.h>

#define NN 50000
#define NE 800000
#define NF 128
#define NH 64
#define LRELU 0.05f
#define NTILES (NN / 16)                    // 3125 (exact)
#define GEMM_BLKS 196                       // x2 tile-iterations x8 waves = 3136 tiles
#define SLOT 64                             // per-node capacity (max deg ~40)
#define BKT 32                              // nodes per bucket
#define NB ((NN + BKT - 1) / BKT)           // 1563 buckets
#define CAP 704                             // per-bucket capacity (load ~512+8.5 sigma)
#define KB (512 - GEMM_BLKS)                // 316 partition blocks -> 512 total = 2/CU
#define EPB ((NE + KB - 1) / KB)            // 2532 edges per block

typedef __attribute__((ext_vector_type(8))) short bf16x8;  // 8 bf16 = 4 VGPR
typedef __attribute__((ext_vector_type(4))) float f32x4;
typedef __attribute__((ext_vector_type(2))) float f32x2;
typedef __attribute__((ext_vector_type(4))) unsigned int u32x4;

static __device__ inline short f2bf(float f) {
    __hip_bfloat16 h = __float2bfloat16(f);
    return *reinterpret_cast<short*>(&h);
}

// ---------------------------------------------------------------------------
// K0: Bt[80][128] bf16: rows 0..63 = W^T, 64 = (W@a1)^T, 65 = (W@a2)^T, pad 0.
// Also zeroes the per-bucket cursor array.
// ---------------------------------------------------------------------------
__global__ __launch_bounds__(128) void k0_build_bt(
    const float* __restrict__ W, const float* __restrict__ a_w,
    __hip_bfloat16* __restrict__ Bt, int* __restrict__ cursor)
{
    const int c = blockIdx.x, k = threadIdx.x;
    const int gid = c * 128 + k;
    if (gid < NB) cursor[gid] = 0;

    float v = 0.f;
    if (c < NH) {
        v = W[k * NH + c];
    } else if (c == NH) {
        #pragma unroll 8
        for (int h = 0; h < NH; ++h) v = fmaf(W[k * NH + h], a_w[h], v);
    } else if (c == NH + 1) {
        #pragma unroll 8
        for (int h = 0; h < NH; ++h) v = fmaf(W[k * NH + h], a_w[NH + h], v);
    }
    Bt[c * NF + k] = __float2bfloat16(v);
}

// ---------------------------------------------------------------------------
// FAT: 512 blocks exactly (2 per CU, enforced by __launch_bounds__(512,4)):
//  - blocks [0, GEMM_BLKS):  MFMA GEMM [z16 | srinv.x | s_src] = x @ Bt^T,
//    2 tile-iterations x 8 waves x 16 rows per block.
//  - blocks [GEMM_BLKS, 512): single-pass edge partition by 32-node bucket:
//    LDS histogram returns in-block rank (5 register slots/thread); ONE
//    global atomicAdd per nonzero (block,bucket); scatter from registers.
// ---------------------------------------------------------------------------
__global__ __launch_bounds__(512, 4) void k_fat(
    const float* __restrict__ x, const __hip_bfloat16* __restrict__ Bt,
    __hip_bfloat16* __restrict__ z16,
    float2* __restrict__ srinv, float* __restrict__ s_src,
    const int* __restrict__ ei, int* __restrict__ cursor,
    unsigned* __restrict__ recs)
{
    __shared__ unsigned hist[NB];    // 6.25 KB (partition role only)
    __shared__ unsigned basel[NB];   // 6.25 KB
    const int tid = threadIdx.x;

    if (blockIdx.x < GEMM_BLKS) {
        // ----- GEMM role -----
        const int wave = tid >> 6, lane = tid & 63;
        const int lrow = lane & 15;
        const int lgrp = lane >> 4;

        #pragma unroll
        for (int it = 0; it < 2; ++it) {
            const int tile = blockIdx.x * 16 + it * 8 + wave;
            if (tile >= NTILES) break;          // tile grows with it -> safe
            const int r0 = tile * 16;

            bf16x8 afrag[4];
            const float* xrow = x + (size_t)(r0 + lrow) * NF + lgrp * 8;
            #pragma unroll
            for (int t = 0; t < 4; ++t) {
                f32x4 u = *(const f32x4*)(xrow + t * 32);
                f32x4 v = *(const f32x4*)(xrow + t * 32 + 4);
                bf16x8 a;
                #pragma unroll
                for (int j = 0; j < 4; ++j) { a[j] = f2bf(u[j]); a[4 + j] = f2bf(v[j]); }
                afrag[t] = a;
            }

            f32x4 acc[5] = {};
            #pragma unroll
            for (int t = 0; t < 4; ++t)
                #pragma unroll
                for (int n = 0; n < 5; ++n) {
                    const bf16x8 b = *(const bf16x8*)&Bt[(n * 16 + lrow) * NF + t * 32 + lgrp * 8];
                    acc[n] = __builtin_amdgcn_mfma_f32_16x16x32_bf16(afrag[t], b, acc[n], 0, 0, 0);
                }

            #pragma unroll
            for (int n = 0; n < 4; ++n)
                #pragma unroll
                for (int r = 0; r < 4; ++r)
                    z16[(size_t)(r0 + lgrp * 4 + r) * NH + n * 16 + lrow] = __float2bfloat16(acc[n][r]);

            #pragma unroll
            for (int r = 0; r < 4; ++r) {
                const int orow = r0 + lgrp * 4 + r;
                if (lrow == 0)      srinv[orow].x = acc[4][r];
                else if (lrow == 1) s_src[orow] = acc[4][r];
            }
        }
    } else {
        // ----- Partition role -----
        const int pb = blockIdx.x - GEMM_BLKS;
        for (int i = tid; i < NB; i += 512) hist[i] = 0;
        __syncthreads();

        const int base = pb * EPB;
        const int lim  = (NE - base < EPB) ? (NE - base) : EPB;

        int      bb0 = -1, bb1 = -1, bb2 = -1, bb3 = -1, bb4 = -1;
        unsigned rk0 = 0, rk1 = 0, rk2 = 0, rk3 = 0, rk4 = 0;
        unsigned pl0 = 0, pl1 = 0, pl2 = 0, pl3 = 0, pl4 = 0;

        #define KC_GRAB(J, BBJ, RKJ, PLJ)                                      \
            { const int i = tid + (J) * 512;                                   \
              if (i < lim) {                                                   \
                  const int d = ei[base + i];                                  \
                  const int s = ei[NE + base + i];                             \
                  BBJ = d >> 5;                                                \
                  RKJ = atomicAdd(&hist[BBJ], 1u);                             \
                  PLJ = (unsigned)s | ((unsigned)(d & 31) << 16);              \
              } }
        KC_GRAB(0, bb0, rk0, pl0)
        KC_GRAB(1, bb1, rk1, pl1)
        KC_GRAB(2, bb2, rk2, pl2)
        KC_GRAB(3, bb3, rk3, pl3)
        KC_GRAB(4, bb4, rk4, pl4)
        #undef KC_GRAB
        __syncthreads();

        for (int b = tid; b < NB; b += 512) {
            const unsigned c = hist[b];
            basel[b] = c ? (unsigned)atomicAdd(&cursor[b], (int)c) : 0u;
        }
        __syncthreads();

        #define KC_PUT(BBJ, RKJ, PLJ)                                          \
            if (BBJ >= 0) {                                                    \
                const unsigned pos = basel[BBJ] + RKJ;                         \
                if (pos < CAP) recs[(size_t)BBJ * CAP + pos] = PLJ;            \
            }
        KC_PUT(bb0, rk0, pl0)
        KC_PUT(bb1, rk1, pl1)
        KC_PUT(bb2, rk2, pl2)
        KC_PUT(bb3, rk3, pl3)
        KC_PUT(bb4, rk4, pl4)
        #undef KC_PUT
    }
}

// ---------------------------------------------------------------------------
// KD: one block (512 thr) per bucket (32 nodes). Stage: read recs (coalesced),
// h = exp(lrelu(sd+ss+b)), bin {src,bf16(h)} into LDS. Aggregate: per-wave
// wide z-gathers (8 lanes x dwordx4 per row = 8 edges per load); out write
// (non-temporal: zero reuse, keep z16 L2-resident) + rinv into srinv[node].y.
// ---------------------------------------------------------------------------
__global__ __launch_bounds__(512) void kD_aggregate(
    const __hip_bfloat16* __restrict__ z16,
    float2* __restrict__ srinv, const float* __restrict__ s_src,
    const float* __restrict__ a_b,
    const unsigned* __restrict__ recs, const int* __restrict__ cursor,
    float* __restrict__ out)
{
    __shared__ unsigned bins[BKT * SLOT];   // 8 KB
    __shared__ unsigned lcnt[BKT];
    __shared__ float    sdl[BKT];
    const int bkt = blockIdx.x;
    const int tid = threadIdx.x;
    const int n0  = bkt * BKT;

    if (tid < BKT) {
        lcnt[tid] = 0;
        sdl[tid] = (n0 + tid < NN) ? srinv[n0 + tid].x : 0.f;
    }
    __syncthreads();

    int tot = cursor[bkt];
    if (tot > CAP) tot = CAP;
    const float bias = a_b[0];

    for (int i = tid; i < tot; i += 512) {
        const unsigned rec = recs[(size_t)bkt * CAP + i];
        const unsigned src = rec & 0xffffu;
        const unsigned dl  = (rec >> 16) & 31u;
        float h = sdl[dl] + s_src[src] + bias;
        h = (h >= 0.f) ? h : LRELU * h;
        h = expf(h);
        const unsigned r = atomicAdd(&lcnt[dl], 1u);
        if (r < SLOT)
            bins[dl * SLOT + r] = src | ((unsigned)(unsigned short)f2bf(h) << 16);
    }
    __syncthreads();

    const int wave = tid >> 6, lane = tid & 63;
    const int sub  = lane >> 3, col8 = lane & 7;
    const char* zb = (const char*)z16;

    for (int dl = wave; dl < BKT; dl += 8) {
        const int node = n0 + dl;
        if (node >= NN) break;
        int deg = (int)__builtin_amdgcn_readfirstlane(lcnt[dl]);
        if (deg > SLOT) deg = SLOT;

        unsigned pv = (lane < deg) ? bins[dl * SLOT + lane] : 0u;
        float hs = __uint_as_float(pv & 0xffff0000u);
        float acc[8] = {0.f, 0.f, 0.f, 0.f, 0.f, 0.f, 0.f, 0.f};

        const int gmax = (deg + 7) >> 3;
        for (int g = 0; g < gmax; ++g) {
            const unsigned pg = (unsigned)__builtin_amdgcn_ds_bpermute(
                ((g << 3) | sub) << 2, (int)pv);
            const float hg = __uint_as_float(pg & 0xffff0000u);
            const unsigned sg = pg & 0xffffu;
            const u32x4 q = *(const u32x4*)(zb + ((size_t)(sg << 7) | (col8 << 4)));
            #pragma unroll
            for (int i = 0; i < 4; ++i) {
                acc[2*i]   = fmaf(hg, __uint_as_float(q[i] << 16),         acc[2*i]);
                acc[2*i+1] = fmaf(hg, __uint_as_float(q[i] & 0xffff0000u), acc[2*i+1]);
            }
        }

        #pragma unroll
        for (int off = 8; off <= 32; off <<= 1)
            #pragma unroll
            for (int i = 0; i < 8; ++i) acc[i] += __shfl_xor(acc[i], off, 64);

        #pragma unroll
        for (int off = 32; off > 0; off >>= 1) hs += __shfl_xor(hs, off, 64);
        const float rinv = (deg > 0) ? 1.f / hs : 0.f;
        if (lane == 0) srinv[node].y = rinv;

        if (lane < 8) {
            f32x4 o0 = {acc[0] * rinv, acc[1] * rinv, acc[2] * rinv, acc[3] * rinv};
            f32x4 o1 = {acc[4] * rinv, acc[5] * rinv, acc[6] * rinv, acc[7] * rinv};
            float* op = out + (size_t)node * NH + lane * 8;
            __builtin_nontemporal_store(o0, (f32x4*)op);
            __builtin_nontemporal_store(o1, (f32x4*)(op + 4));
        }
    }
}

// ---------------------------------------------------------------------------
// K7: alpha[e] = exp(lrelu(srinv[d].x + s_src[s] + b)) * srinv[d].y.
// 2 edges/thread: int2 ei loads, 2 independent gather chains, f32x2 NT store.
// 400K threads (~24 waves/CU) keeps TLP ample while halving per-edge overhead.
// ---------------------------------------------------------------------------
__global__ __launch_bounds__(256) void k7_alpha(
    const int* __restrict__ ei,
    const float2* __restrict__ srinv, const float* __restrict__ s_src,
    const float* __restrict__ a_b,
    float* __restrict__ alpha)
{
    const int e0 = (blockIdx.x * 256 + threadIdx.x) * 2;
    if (e0 >= NE) return;                       // NE % 2 == 0
    const int2 d2 = *(const int2*)(ei + e0);
    const int2 s2 = *(const int2*)(ei + NE + e0);
    const float b = a_b[0];

    const float2 sr0 = srinv[d2.x];
    const float2 sr1 = srinv[d2.y];
    float h0 = sr0.x + s_src[s2.x] + b;
    float h1 = sr1.x + s_src[s2.y] + b;
    h0 = (h0 >= 0.f) ? h0 : LRELU * h0;
    h1 = (h1 >= 0.f) ? h1 : LRELU * h1;
    f32x2 a;
    a[0] = expf(h0) * sr0.y;
    a[1] = expf(h1) * sr1.y;
    __builtin_nontemporal_store(a, (f32x2*)(alpha + e0));
}

// ---------------------------------------------------------------------------
extern "C" void kernel_launch(void* const* d_in, const int* in_sizes, int n_in,
                              void* d_out, int out_size, void* d_ws, size_t ws_size,
                              hipStream_t stream) {
    const float* x   = (const float*)d_in[0];
    const int*   ei  = (const int*)d_in[1];   // [2*E]: row0 = dst, row1 = src
    const float* W   = (const float*)d_in[2];
    const float* a_w = (const float*)d_in[3];
    const float* a_b = (const float*)d_in[4];

    float* out   = (float*)d_out;                     // [N*64]
    float* alpha = out + (size_t)NN * NH;             // [E]

    // workspace layout (~12 MB)
    __hip_bfloat16* z16 = (__hip_bfloat16*)d_ws;          // [N*64]   6.4 MB
    __hip_bfloat16* Bt  = z16 + (size_t)NN * NH;          // [80*128] 20 KB
    float2* srinv = (float2*)(Bt + 80 * NF);              // [N] {s_dst, rinv}
    float* s_src  = (float*)(srinv + NN);                 // [N]
    int* cursor   = (int*)(s_src + NN);                   // [NB]
    unsigned* recs = (unsigned*)(cursor + NB);            // [NB*CAP] 4.4 MB

    k0_build_bt <<<80, 128, 0, stream>>>(W, a_w, Bt, cursor);
    k_fat       <<<512, 512, 0, stream>>>(x, Bt, z16, srinv, s_src, ei, cursor, recs);
    kD_aggregate<<<NB, 512, 0, stream>>>(z16, srinv, s_src, a_b, recs, cursor, out);
    k7_alpha    <<<(NE / 2 + 255) / 256, 256, 0, stream>>>(ei, srinv, s_src, a_b, alpha);
}

// Round 24
// 68.614 us; speedup vs baseline: 1.0084x; 1.0084x over previous
//
#include <hip/hip_runtime.h>
#include <hip/hip_bf16.h>

#define NN 50000
#define NE 800000
#define NF 128
#define NH 64
#define LRELU 0.05f
#define NTILES (NN / 16)                    // 3125 (exact)
#define GEMM_BLKS 196                       // x2 tile-iterations x8 waves = 3136 tiles
#define SLOT 64                             // per-node capacity (max deg ~40)
#define BKT 32                              // nodes per bucket
#define NB ((NN + BKT - 1) / BKT)           // 1563 buckets
#define CAP 704                             // per-bucket capacity (load ~512+8.5 sigma)
#define KB (512 - GEMM_BLKS)                // 316 partition blocks -> 512 total = 2/CU
#define EPB ((NE + KB - 1) / KB)            // 2532 edges per block

typedef __attribute__((ext_vector_type(8))) short bf16x8;  // 8 bf16 = 4 VGPR
typedef __attribute__((ext_vector_type(4))) float f32x4;
typedef __attribute__((ext_vector_type(4))) unsigned int u32x4;

static __device__ inline short f2bf(float f) {
    __hip_bfloat16 h = __float2bfloat16(f);
    return *reinterpret_cast<short*>(&h);
}

// ---------------------------------------------------------------------------
// K0: Bt[80][128] bf16: rows 0..63 = W^T, 64 = (W@a1)^T, 65 = (W@a2)^T, pad 0.
// Also zeroes the per-bucket cursor array.
// ---------------------------------------------------------------------------
__global__ __launch_bounds__(128) void k0_build_bt(
    const float* __restrict__ W, const float* __restrict__ a_w,
    __hip_bfloat16* __restrict__ Bt, int* __restrict__ cursor)
{
    const int c = blockIdx.x, k = threadIdx.x;
    const int gid = c * 128 + k;
    if (gid < NB) cursor[gid] = 0;

    float v = 0.f;
    if (c < NH) {
        v = W[k * NH + c];
    } else if (c == NH) {
        #pragma unroll 8
        for (int h = 0; h < NH; ++h) v = fmaf(W[k * NH + h], a_w[h], v);
    } else if (c == NH + 1) {
        #pragma unroll 8
        for (int h = 0; h < NH; ++h) v = fmaf(W[k * NH + h], a_w[NH + h], v);
    }
    Bt[c * NF + k] = __float2bfloat16(v);
}

// ---------------------------------------------------------------------------
// FAT: 512 blocks exactly (2 per CU, enforced by __launch_bounds__(512,4)):
//  - blocks [0, GEMM_BLKS):  MFMA GEMM [z16 | srinv.x | s_src] = x @ Bt^T,
//    2 tile-iterations x 8 waves x 16 rows per block.
//  - blocks [GEMM_BLKS, 512): single-pass edge partition by 32-node bucket:
//    LDS histogram returns in-block rank (5 register slots/thread); ONE
//    global atomicAdd per nonzero (block,bucket); scatter from registers.
// ---------------------------------------------------------------------------
__global__ __launch_bounds__(512, 4) void k_fat(
    const float* __restrict__ x, const __hip_bfloat16* __restrict__ Bt,
    __hip_bfloat16* __restrict__ z16,
    float2* __restrict__ srinv, float* __restrict__ s_src,
    const int* __restrict__ ei, int* __restrict__ cursor,
    unsigned* __restrict__ recs)
{
    __shared__ unsigned hist[NB];    // 6.25 KB (partition role only)
    __shared__ unsigned basel[NB];   // 6.25 KB
    const int tid = threadIdx.x;

    if (blockIdx.x < GEMM_BLKS) {
        // ----- GEMM role -----
        const int wave = tid >> 6, lane = tid & 63;
        const int lrow = lane & 15;
        const int lgrp = lane >> 4;

        #pragma unroll
        for (int it = 0; it < 2; ++it) {
            const int tile = blockIdx.x * 16 + it * 8 + wave;
            if (tile >= NTILES) break;          // tile grows with it -> safe
            const int r0 = tile * 16;

            bf16x8 afrag[4];
            const float* xrow = x + (size_t)(r0 + lrow) * NF + lgrp * 8;
            #pragma unroll
            for (int t = 0; t < 4; ++t) {
                f32x4 u = *(const f32x4*)(xrow + t * 32);
                f32x4 v = *(const f32x4*)(xrow + t * 32 + 4);
                bf16x8 a;
                #pragma unroll
                for (int j = 0; j < 4; ++j) { a[j] = f2bf(u[j]); a[4 + j] = f2bf(v[j]); }
                afrag[t] = a;
            }

            f32x4 acc[5] = {};
            #pragma unroll
            for (int t = 0; t < 4; ++t)
                #pragma unroll
                for (int n = 0; n < 5; ++n) {
                    const bf16x8 b = *(const bf16x8*)&Bt[(n * 16 + lrow) * NF + t * 32 + lgrp * 8];
                    acc[n] = __builtin_amdgcn_mfma_f32_16x16x32_bf16(afrag[t], b, acc[n], 0, 0, 0);
                }

            #pragma unroll
            for (int n = 0; n < 4; ++n)
                #pragma unroll
                for (int r = 0; r < 4; ++r)
                    z16[(size_t)(r0 + lgrp * 4 + r) * NH + n * 16 + lrow] = __float2bfloat16(acc[n][r]);

            #pragma unroll
            for (int r = 0; r < 4; ++r) {
                const int orow = r0 + lgrp * 4 + r;
                if (lrow == 0)      srinv[orow].x = acc[4][r];
                else if (lrow == 1) s_src[orow] = acc[4][r];
            }
        }
    } else {
        // ----- Partition role -----
        const int pb = blockIdx.x - GEMM_BLKS;
        for (int i = tid; i < NB; i += 512) hist[i] = 0;
        __syncthreads();

        const int base = pb * EPB;
        const int lim  = (NE - base < EPB) ? (NE - base) : EPB;

        int      bb0 = -1, bb1 = -1, bb2 = -1, bb3 = -1, bb4 = -1;
        unsigned rk0 = 0, rk1 = 0, rk2 = 0, rk3 = 0, rk4 = 0;
        unsigned pl0 = 0, pl1 = 0, pl2 = 0, pl3 = 0, pl4 = 0;

        #define KC_GRAB(J, BBJ, RKJ, PLJ)                                      \
            { const int i = tid + (J) * 512;                                   \
              if (i < lim) {                                                   \
                  const int d = ei[base + i];                                  \
                  const int s = ei[NE + base + i];                             \
                  BBJ = d >> 5;                                                \
                  RKJ = atomicAdd(&hist[BBJ], 1u);                             \
                  PLJ = (unsigned)s | ((unsigned)(d & 31) << 16);              \
              } }
        KC_GRAB(0, bb0, rk0, pl0)
        KC_GRAB(1, bb1, rk1, pl1)
        KC_GRAB(2, bb2, rk2, pl2)
        KC_GRAB(3, bb3, rk3, pl3)
        KC_GRAB(4, bb4, rk4, pl4)
        #undef KC_GRAB
        __syncthreads();

        for (int b = tid; b < NB; b += 512) {
            const unsigned c = hist[b];
            basel[b] = c ? (unsigned)atomicAdd(&cursor[b], (int)c) : 0u;
        }
        __syncthreads();

        #define KC_PUT(BBJ, RKJ, PLJ)                                          \
            if (BBJ >= 0) {                                                    \
                const unsigned pos = basel[BBJ] + RKJ;                         \
                if (pos < CAP) recs[(size_t)BBJ * CAP + pos] = PLJ;            \
            }
        KC_PUT(bb0, rk0, pl0)
        KC_PUT(bb1, rk1, pl1)
        KC_PUT(bb2, rk2, pl2)
        KC_PUT(bb3, rk3, pl3)
        KC_PUT(bb4, rk4, pl4)
        #undef KC_PUT
    }
}

// ---------------------------------------------------------------------------
// KD: one block (512 thr) per bucket (32 nodes). Stage: read recs (coalesced),
// h = exp(lrelu(sd+ss+b)), bin {src,bf16(h)} into LDS. Aggregate: per-wave
// wide z-gathers (8 lanes x dwordx4 per row = 8 edges per load); out write
// (non-temporal: zero reuse, keep z16 L2-resident) + rinv into srinv[node].y.
// ---------------------------------------------------------------------------
__global__ __launch_bounds__(512) void kD_aggregate(
    const __hip_bfloat16* __restrict__ z16,
    float2* __restrict__ srinv, const float* __restrict__ s_src,
    const float* __restrict__ a_b,
    const unsigned* __restrict__ recs, const int* __restrict__ cursor,
    float* __restrict__ out)
{
    __shared__ unsigned bins[BKT * SLOT];   // 8 KB
    __shared__ unsigned lcnt[BKT];
    __shared__ float    sdl[BKT];
    const int bkt = blockIdx.x;
    const int tid = threadIdx.x;
    const int n0  = bkt * BKT;

    if (tid < BKT) {
        lcnt[tid] = 0;
        sdl[tid] = (n0 + tid < NN) ? srinv[n0 + tid].x : 0.f;
    }
    __syncthreads();

    int tot = cursor[bkt];
    if (tot > CAP) tot = CAP;
    const float bias = a_b[0];

    for (int i = tid; i < tot; i += 512) {
        const unsigned rec = recs[(size_t)bkt * CAP + i];
        const unsigned src = rec & 0xffffu;
        const unsigned dl  = (rec >> 16) & 31u;
        float h = sdl[dl] + s_src[src] + bias;
        h = (h >= 0.f) ? h : LRELU * h;
        h = expf(h);
        const unsigned r = atomicAdd(&lcnt[dl], 1u);
        if (r < SLOT)
            bins[dl * SLOT + r] = src | ((unsigned)(unsigned short)f2bf(h) << 16);
    }
    __syncthreads();

    const int wave = tid >> 6, lane = tid & 63;
    const int sub  = lane >> 3, col8 = lane & 7;
    const char* zb = (const char*)z16;

    for (int dl = wave; dl < BKT; dl += 8) {
        const int node = n0 + dl;
        if (node >= NN) break;
        int deg = (int)__builtin_amdgcn_readfirstlane(lcnt[dl]);
        if (deg > SLOT) deg = SLOT;

        unsigned pv = (lane < deg) ? bins[dl * SLOT + lane] : 0u;
        float hs = __uint_as_float(pv & 0xffff0000u);
        float acc[8] = {0.f, 0.f, 0.f, 0.f, 0.f, 0.f, 0.f, 0.f};

        const int gmax = (deg + 7) >> 3;
        for (int g = 0; g < gmax; ++g) {
            const unsigned pg = (unsigned)__builtin_amdgcn_ds_bpermute(
                ((g << 3) | sub) << 2, (int)pv);
            const float hg = __uint_as_float(pg & 0xffff0000u);
            const unsigned sg = pg & 0xffffu;
            const u32x4 q = *(const u32x4*)(zb + ((size_t)(sg << 7) | (col8 << 4)));
            #pragma unroll
            for (int i = 0; i < 4; ++i) {
                acc[2*i]   = fmaf(hg, __uint_as_float(q[i] << 16),         acc[2*i]);
                acc[2*i+1] = fmaf(hg, __uint_as_float(q[i] & 0xffff0000u), acc[2*i+1]);
            }
        }

        #pragma unroll
        for (int off = 8; off <= 32; off <<= 1)
            #pragma unroll
            for (int i = 0; i < 8; ++i) acc[i] += __shfl_xor(acc[i], off, 64);

        #pragma unroll
        for (int off = 32; off > 0; off >>= 1) hs += __shfl_xor(hs, off, 64);
        const float rinv = (deg > 0) ? 1.f / hs : 0.f;
        if (lane == 0) srinv[node].y = rinv;

        if (lane < 8) {
            f32x4 o0 = {acc[0] * rinv, acc[1] * rinv, acc[2] * rinv, acc[3] * rinv};
            f32x4 o1 = {acc[4] * rinv, acc[5] * rinv, acc[6] * rinv, acc[7] * rinv};
            float* op = out + (size_t)node * NH + lane * 8;
            __builtin_nontemporal_store(o0, (f32x4*)op);
            __builtin_nontemporal_store(o1, (f32x4*)(op + 4));
        }
    }
}

// ---------------------------------------------------------------------------
// K7: alpha[e] = exp(lrelu(srinv[d].x + s_src[s] + b)) * srinv[d].y.
// One 8B gather (srinv) + one 4B gather (s_src) per edge; alpha written
// non-temporal (streaming, zero reuse -> keep gather tables in L2).
// ---------------------------------------------------------------------------
__global__ __launch_bounds__(256) void k7_alpha(
    const int* __restrict__ ei,
    const float2* __restrict__ srinv, const float* __restrict__ s_src,
    const float* __restrict__ a_b,
    float* __restrict__ alpha)
{
    const int e = blockIdx.x * 256 + threadIdx.x;
    if (e >= NE) return;
    const int d = ei[e];
    const int s = ei[NE + e];
    const float2 sr = srinv[d];
    float h = sr.x + s_src[s] + a_b[0];
    h = (h >= 0.f) ? h : LRELU * h;
    __builtin_nontemporal_store(expf(h) * sr.y, alpha + e);
}

// ---------------------------------------------------------------------------
extern "C" void kernel_launch(void* const* d_in, const int* in_sizes, int n_in,
                              void* d_out, int out_size, void* d_ws, size_t ws_size,
                              hipStream_t stream) {
    const float* x   = (const float*)d_in[0];
    const int*   ei  = (const int*)d_in[1];   // [2*E]: row0 = dst, row1 = src
    const float* W   = (const float*)d_in[2];
    const float* a_w = (const float*)d_in[3];
    const float* a_b = (const float*)d_in[4];

    float* out   = (float*)d_out;                     // [N*64]
    float* alpha = out + (size_t)NN * NH;             // [E]

    // workspace layout (~12 MB)
    __hip_bfloat16* z16 = (__hip_bfloat16*)d_ws;          // [N*64]   6.4 MB
    __hip_bfloat16* Bt  = z16 + (size_t)NN * NH;          // [80*128] 20 KB
    float2* srinv = (float2*)(Bt + 80 * NF);              // [N] {s_dst, rinv}
    float* s_src  = (float*)(srinv + NN);                 // [N]
    int* cursor   = (int*)(s_src + NN);                   // [NB]
    unsigned* recs = (unsigned*)(cursor + NB);            // [NB*CAP] 4.4 MB

    k0_build_bt <<<80, 128, 0, stream>>>(W, a_w, Bt, cursor);
    k_fat       <<<512, 512, 0, stream>>>(x, Bt, z16, srinv, s_src, ei, cursor, recs);
    kD_aggregate<<<NB, 512, 0, stream>>>(z16, srinv, s_src, a_b, recs, cursor, out);
    k7_alpha    <<<(NE + 255) / 256, 256, 0, stream>>>(ei, srinv, s_src, a_b, alpha);
}